// Round 7
// baseline (561.206 us; speedup 1.0000x reference)
//
#include <hip/hip_runtime.h>

#define NBINS 16
#define TPB   256
#define GRID  1024          // 4 blocks/CU exactly co-resident (VGPR-bound ~4 waves/SIMD)

// d_ws layout: partial[c * GRID + blk], c: 0..15 sum, 16..31 sumsq, 32..47 cnt,
// 48 = sum (wq-w)^2.  cells[49] at partial + 49*GRID.
//
// History: LDS atomics (R1 CAS 1026us, R3 ds_add 1010us) >> plain LDS RMW
// (R2/R4/R6: 163-188us) -- but R2==R4==R6 despite 3x different DS op counts,
// conflicts, occupancy, prefetch: the data-dependent LDS RMW chain imposes a
// ~4600 cyc/iter wave-serial latency floor no pipe explains. R7: NO LDS in the
// hot loop -- per-bin {s,ss} in registers via branchless selects (4 VALU per
// bin per element), counts in a nibble-packed uint64. Pure pipelined VALU.

__global__ __launch_bounds__(TPB) void binreg_main(
    const float* __restrict__ w, const float* __restrict__ wq,
    const float* __restrict__ alpha_p, const int* __restrict__ nbit_p,
    float* __restrict__ partial, long long n)
{
    const int tid = threadIdx.x;

    const float inv_a = 1.0f / alpha_p[0];
    const int   qoff  = 1 << (nbit_p[0] - 1);   // 8 for nbit=4

    float accS [NBINS];   // per-thread per-bin sum of w
    float accSS[NBINS];   // per-thread per-bin sum of w^2
    int   cnt  [NBINS];
    #pragma unroll
    for (int k = 0; k < NBINS; ++k) { accS[k] = 0.f; accSS[k] = 0.f; cnt[k] = 0; }

    float sq = 0.0f;
    unsigned long long nib = 0ull;   // 16 x 4-bit counters; 4 adds/iter, flush@3 (<=12 < 16)
    int fc = 3;

    const long long n4     = n >> 2;
    const long long stride = (long long)GRID * TPB;
    const float4* w4 = (const float4*)w;
    const float4* q4 = (const float4*)wq;

    for (long long i = (long long)blockIdx.x * TPB + tid; i < n4; i += stride) {
        float4 a = w4[i];
        float4 b = q4[i];

        float d0 = b.x - a.x, d1 = b.y - a.y, d2 = b.z - a.z, d3 = b.w - a.w;
        sq += d0 * d0 + d1 * d1 + d2 * d2 + d3 * d3;

        int b0 = ((int)rintf(b.x * inv_a) + qoff) & (NBINS - 1);
        int b1 = ((int)rintf(b.y * inv_a) + qoff) & (NBINS - 1);
        int b2 = ((int)rintf(b.z * inv_a) + qoff) & (NBINS - 1);
        int b3 = ((int)rintf(b.w * inv_a) + qoff) & (NBINS - 1);

        nib += (1ull << (b0 << 2)) + (1ull << (b1 << 2))
             + (1ull << (b2 << 2)) + (1ull << (b3 << 2));
        if (--fc == 0) {
            #pragma unroll
            for (int k = 0; k < NBINS; ++k)
                cnt[k] += (int)((nib >> (k * 4)) & 0xFull);
            nib = 0ull; fc = 3;
        }

        // register-resident binned accumulation: cmp + cndmask + add + fmac
        // per (bin, element); sel^2 = w^2 * [bin==k] for free via fmac(sel,sel)
        #pragma unroll
        for (int k = 0; k < NBINS; ++k) {
            float s0 = (b0 == k) ? a.x : 0.0f;
            float s1 = (b1 == k) ? a.y : 0.0f;
            float s2 = (b2 == k) ? a.z : 0.0f;
            float s3 = (b3 == k) ? a.w : 0.0f;
            accS [k] += (s0 + s1) + (s2 + s3);
            accSS[k] = fmaf(s0, s0, accSS[k]);
            accSS[k] = fmaf(s1, s1, accSS[k]);
            accSS[k] = fmaf(s2, s2, accSS[k]);
            accSS[k] = fmaf(s3, s3, accSS[k]);
        }
    }

    // scalar tail (n divisible by 4 in practice; safety only)
    for (long long t4 = (n4 << 2) + (long long)blockIdx.x * TPB + tid; t4 < n; t4 += stride) {
        float av = w[t4], bv = wq[t4];
        float d = bv - av;
        sq += d * d;
        int bb = ((int)rintf(bv * inv_a) + qoff) & (NBINS - 1);
        nib += 1ull << (bb << 2);
        #pragma unroll
        for (int k = 0; k < NBINS; ++k) {
            float s0 = (bb == k) ? av : 0.0f;
            accS [k] += s0;
            accSS[k] = fmaf(s0, s0, accSS[k]);
        }
    }
    #pragma unroll
    for (int k = 0; k < NBINS; ++k)
        cnt[k] += (int)((nib >> (k * 4)) & 0xFull);

    // ---- epilogue: wave-shuffle reduce 49 cells, tiny LDS stage ----
    __shared__ float stage[4 * 49];
    const int wave = tid >> 6, lane = tid & 63;

    #pragma unroll
    for (int c = 0; c < 49; ++c) {
        float v = (c < 16) ? accS[c]
                : (c < 32) ? accSS[c - 16]
                : (c < 48) ? (float)cnt[c - 32]
                : sq;
        for (int off = 32; off; off >>= 1) v += __shfl_down(v, off, 64);
        if (lane == 0) stage[wave * 49 + c] = v;
    }
    __syncthreads();

    if (tid < 49)
        partial[tid * GRID + blockIdx.x] =
            (stage[tid] + stage[49 + tid]) + (stage[98 + tid] + stage[147 + tid]);
}

// stage 1: one block per cell, reduce GRID partials -> cells[c]
__global__ __launch_bounds__(TPB) void binreg_final1(
    const float* __restrict__ partial, float* __restrict__ cells)
{
    const int c = blockIdx.x;
    const int tid = threadIdx.x, wave = tid >> 6, lane = tid & 63;
    __shared__ float wsum[4];

    float v = 0.0f;
    for (int r = tid; r < GRID; r += TPB) v += partial[c * GRID + r];
    for (int off = 32; off; off >>= 1) v += __shfl_down(v, off, 64);
    if (lane == 0) wsum[wave] = v;
    __syncthreads();
    if (tid == 0) cells[c] = (wsum[0] + wsum[1]) + (wsum[2] + wsum[3]);
}

// stage 2: combine 49 cells into the loss scalar
__global__ void binreg_final2(const float* __restrict__ cells,
                              float* __restrict__ out, long long n)
{
    if (threadIdx.x == 0 && blockIdx.x == 0) {
        float loss = cells[48] / (float)n;   // mean squared diff
        #pragma unroll
        for (int b = 0; b < NBINS; ++b) {
            float s   = cells[b];
            float ss  = cells[16 + b];
            float cnt = cells[32 + b];
            if (cnt > 1.0f)
                loss += (ss - s * s / cnt) / (cnt - 1.0f);  // unbiased var
        }
        out[0] = 0.1f * loss;   // LMBDA
    }
}

extern "C" void kernel_launch(void* const* d_in, const int* in_sizes, int n_in,
                              void* d_out, int out_size, void* d_ws, size_t ws_size,
                              hipStream_t stream)
{
    const float* w     = (const float*)d_in[0];
    const float* wq    = (const float*)d_in[1];
    const int*   nbit  = (const int*)d_in[2];
    const float* alpha = (const float*)d_in[3];
    float* out     = (float*)d_out;
    float* partial = (float*)d_ws;            // 49*GRID floats, fully overwritten
    float* cells   = partial + 49 * GRID;     // 49 floats
    long long n = (long long)in_sizes[0];

    binreg_main  <<<GRID, TPB, 0, stream>>>(w, wq, alpha, nbit, partial, n);
    binreg_final1<<<49,   TPB, 0, stream>>>(partial, cells);
    binreg_final2<<<1,    64,  0, stream>>>(cells, out, n);
}